// Round 8
// baseline (521.490 us; speedup 1.0000x reference)
//
#include <hip/hip_runtime.h>
#include <math.h>

#define IMG 112
#define CIN 64
#define CH 256
#define PADW 114
#define IMG2 12544   // 112*112
#define NPIX 25088   // 2*112*112
#define SCQ 0.17677669529663687f

typedef __bf16 bf16;
typedef __bf16 bf16x8 __attribute__((ext_vector_type(8)));
typedef float f32x4 __attribute__((ext_vector_type(4)));

// ---------------- prep: pad images (+zero borders) + all weight transposes ----------------
__global__ __launch_bounds__(256) void prep_kernel(
    const float* __restrict__ xq, const float* __restrict__ xkv,
    bf16* __restrict__ padq, bf16* __restrict__ padkv,
    const float* __restrict__ c1w, const float* __restrict__ c3w,
    bf16* __restrict__ cw1, bf16* __restrict__ cw2,
    const float* __restrict__ wq, bf16* __restrict__ wqt,
    const float* __restrict__ wkv, bf16* __restrict__ wkvt,
    const float* __restrict__ wp, bf16* __restrict__ wpt,
    const float* __restrict__ f1w, bf16* __restrict__ wf1,
    const float* __restrict__ f2w, bf16* __restrict__ wf2) {
    int bid = blockIdx.x, tid = threadIdx.x;
    __shared__ float lds[CIN * 113];
    if (bid < 448) {
        const float* in = (bid < 224) ? xq : xkv;
        bf16* out = (bid < 224) ? padq : padkv;
        int bi = (bid < 224) ? bid : bid - 224;
        int b = bi / IMG, i = bi % IMG;
        const float* src = in + (size_t)b * CIN * IMG2 + (size_t)i * IMG;
        for (int t = tid; t < CIN * IMG; t += 256) {
            int ci = t / IMG, j = t - ci * IMG;
            lds[ci * 113 + j] = src[(size_t)ci * IMG2 + j];
        }
        __syncthreads();
        bf16* dst = out + (((size_t)(b * PADW + (i + 1)) * PADW) + 1) * CIN;
        for (int t = tid; t < CIN * IMG; t += 256) {
            int j = t / CIN, ci = t - j * CIN;
            dst[(size_t)j * CIN + ci] = (bf16)lds[ci * 113 + j];
        }
        bf16* rowbase = out + ((size_t)(b * PADW + (i + 1)) * PADW) * CIN;
        if (tid < 128) rowbase[(tid >> 6 ? 113 * CIN : 0) + (tid & 63)] = (bf16)0.0f;
        if (i == 0)
            for (int t = tid; t < PADW * CIN; t += 256)
                out[((size_t)(b * PADW + 0) * PADW) * CIN + t] = (bf16)0.0f;
        if (i == IMG - 1)
            for (int t = tid; t < PADW * CIN; t += 256)
                out[((size_t)(b * PADW + 113) * PADW) * CIN + t] = (bf16)0.0f;
    } else if (bid < 1024) {
        int idx = (bid - 448) * 256 + tid;
        int co = idx / 576, r = idx - co * 576;
        int tap = r >> 6, ci = r & 63;
        int src = co * 576 + ci * 9 + tap;
        cw1[idx] = (bf16)c1w[src];
        cw2[idx] = (bf16)c3w[src];
    } else {
        int off = (bid - 1024) * 256 + tid;
        const float* in; bf16* out; int K, N; float sc = 1.0f; int base;
        if (off < 65536)       { in = wq;  out = wqt;  K = 256; N = 256; sc = SCQ; base = 0; }
        else if (off < 196608) { in = wkv; out = wkvt; K = 256; N = 512; base = 65536; }
        else if (off < 262144) { in = wp;  out = wpt;  K = 256; N = 256; base = 196608; }
        else if (off < 393216) { in = f1w; out = wf1;  K = 256; N = 512; base = 262144; }
        else                   { in = f2w; out = wf2;  K = 512; N = 256; base = 393216; }
        int idx = off - base;
        int n = idx / K, k = idx - n * K;
        out[idx] = (bf16)(in[(size_t)k * N + n] * sc);
    }
}

// ---------------- direct-to-register GEMM: 32x256 tile, 4 waves (2x2 -> 16x128/wave) ----------------
// No LDS staging, no K-loop barriers. LDS only for the epilogue transpose.
// MODE: 0=dense bf16; 1=LN->two bf16; 2=res+raw+LN; 3=gelu->bf16; 4=f32 NCHW+res
#define M_DENSE 0
#define M_LN2   1
#define M_WPLN  2
#define M_GELU  3
#define M_NCHW  4
#define TS 264   // bf16 transpose-buffer stride, col-XOR swizzled
#define TFS 257  // f32 transpose-buffer stride

template <int AMODE, int MODE, int KK>
__device__ __forceinline__ void gemm_core(
    char* sm,
    const bf16* __restrict__ A, const bf16* __restrict__ B,
    const float* __restrict__ bias, float bscale,
    const bf16* __restrict__ res,
    bf16* __restrict__ out0, int ldo0,
    bf16* __restrict__ out1, float* __restrict__ outf,
    const float* __restrict__ lnw0, const float* __restrict__ lnb0,
    const float* __restrict__ lnw1, const float* __restrict__ lnb1) {
    constexpr int NK = KK >> 6;
    bf16* Tb = (bf16*)sm;                 // [32][TS]  16.9 KB
    float* Tf = (float*)sm;               // [32][TFS] 32.9 KB (NCHW)
    float* lnb = (float*)(sm + 33024);    // 128 f32

    const int tid = threadIdx.x;
    const int wave = tid >> 6, lane = tid & 63;
    const int wm = wave >> 1, wn = wave & 1;
    const int fr = lane & 15, fq = lane >> 4;
    const int m0 = blockIdx.x * 32;

    // per-lane A base: row = m0 + wm*16 + fr, k-offset fq*8 folded in
    const bf16* baseA;
    {
        int arow = m0 + wm * 16 + fr;
        if (AMODE == 1) {
            int b = arow / IMG2;
            int rem = arow - b * IMG2;
            int i = rem / IMG, j = rem - i * IMG;
            baseA = A + ((size_t)((b * PADW + i) * PADW + j)) * CIN + fq * 8;
        } else {
            baseA = A + (size_t)arow * KK + fq * 8;
        }
    }
    const bf16* baseB[8];
#pragma unroll
    for (int ni = 0; ni < 8; ++ni)
        baseB[ni] = B + (size_t)(wn * 128 + ni * 16 + fr) * KK + fq * 8;

    f32x4 acc[8] = {};
#pragma unroll
    for (int kt = 0; kt < NK; ++kt) {
        const int aoff = (AMODE == 1) ? ((kt / 3) * PADW + (kt % 3)) * CIN : kt * 64;
#pragma unroll
        for (int ks = 0; ks < 2; ++ks) {
            bf16x8 av = *(const bf16x8*)(baseA + aoff + ks * 32);
            bf16x8 bv[8];
#pragma unroll
            for (int ni = 0; ni < 8; ++ni)
                bv[ni] = *(const bf16x8*)(baseB[ni] + kt * 64 + ks * 32);
#pragma unroll
            for (int ni = 0; ni < 8; ++ni)
                acc[ni] = __builtin_amdgcn_mfma_f32_16x16x32_bf16(av, bv[ni], acc[ni], 0, 0, 0);
        }
    }

    // ---- acc-space epilogue: bias (+res) (+gelu) ----
#pragma unroll
    for (int ni = 0; ni < 8; ++ni) {
        int col = wn * 128 + ni * 16 + fr;
        float bv = bias[col] * bscale;
#pragma unroll
        for (int r = 0; r < 4; ++r) {
            float x = acc[ni][r] + bv;
            if (MODE == M_WPLN) {
                int prow = m0 + wm * 16 + fq * 4 + r;
                x += (float)res[(size_t)prow * 256 + col];
            }
            if (MODE == M_GELU) x = 0.5f * x * (1.0f + erff(x * 0.70710678118f));
            acc[ni][r] = x;
        }
    }

    const int rloc0 = wm * 16 + fq * 4;   // local row of acc[.][0]

    // ---- LN stats (M_LN2, M_WPLN): 128-col partials -> lnb -> combine halves ----
    if (MODE == M_LN2 || MODE == M_WPLN) {
#pragma unroll
        for (int r = 0; r < 4; ++r) {
            float s = 0.0f, ss = 0.0f;
#pragma unroll
            for (int ni = 0; ni < 8; ++ni) {
                float x = acc[ni][r];
                s += x; ss += x * x;
            }
#pragma unroll
            for (int msk = 1; msk <= 8; msk <<= 1) {
                s += __shfl_xor(s, msk);
                ss += __shfl_xor(ss, msk);
            }
            if (fr == 0) {
                lnb[wn * 64 + rloc0 + r] = s;
                lnb[wn * 64 + 32 + rloc0 + r] = ss;
            }
        }
        __syncthreads();
    }

    if (MODE == M_NCHW) {
        // Tf[pixel][ch] f32 with residual fused at write
#pragma unroll
        for (int ni = 0; ni < 8; ++ni) {
            int col = wn * 128 + ni * 16 + fr;
#pragma unroll
            for (int r = 0; r < 4; ++r) {
                int prow = m0 + rloc0 + r;
                Tf[(rloc0 + r) * TFS + col] = acc[ni][r] + (float)res[(size_t)prow * 256 + col];
            }
        }
        __syncthreads();
        // full-line stores: 8 lanes x 16B = 128B contiguous per channel
        int b = m0 / IMG2, p0 = m0 - b * IMG2;
#pragma unroll
        for (int it = 0; it < 8; ++it) {
            int ch = it * 32 + (tid >> 3);
            int px = (tid & 7) * 4;
            f32x4 v;
#pragma unroll
            for (int e = 0; e < 4; ++e) v[e] = Tf[(px + e) * TFS + ch];
            *(f32x4*)(outf + ((size_t)(b * CH + ch)) * IMG2 + p0 + px) = v;
        }
    } else {
        // LN2 normalizes before Tb; DENSE/GELU/WPLN write raw
        float mean_[4], rstd_[4];
        if (MODE == M_LN2) {
#pragma unroll
            for (int r = 0; r < 4; ++r) {
                float s = lnb[rloc0 + r] + lnb[64 + rloc0 + r];
                float ss = lnb[32 + rloc0 + r] + lnb[96 + rloc0 + r];
                float mean = s * (1.0f / CH);
                mean_[r] = mean;
                rstd_[r] = rsqrtf(ss * (1.0f / CH) - mean * mean + 1e-5f);
            }
        }
#pragma unroll
        for (int ni = 0; ni < 8; ++ni) {
            int col = wn * 128 + ni * 16 + fr;
#pragma unroll
            for (int r = 0; r < 4; ++r) {
                int row = rloc0 + r;
                float x = acc[ni][r];
                if (MODE == M_LN2) x = (x - mean_[r]) * rstd_[r];
                Tb[row * TS + (col ^ ((row & 7) << 3))] = (bf16)x;
            }
        }
        __syncthreads();
        // full-line stores: 32 lanes x 16B = 512B contiguous per row
#pragma unroll
        for (int it = 0; it < 4; ++it) {
            int row = it * 8 + (tid >> 5);
            int col = (tid & 31) * 8;
            bf16x8 v = *(const bf16x8*)&Tb[row * TS + (col ^ ((row & 7) << 3))];
            if (MODE == M_DENSE || MODE == M_GELU) {
                *(bf16x8*)(out0 + (size_t)(m0 + row) * ldo0 + col) = v;
            } else if (MODE == M_LN2) {
                bf16x8 o0, o1;
#pragma unroll
                for (int e = 0; e < 8; ++e) {
                    int c = col + e;
                    float xh = (float)v[e];
                    o0[e] = (bf16)(xh * lnw0[c] + lnb0[c]);
                    o1[e] = (bf16)(xh * lnw1[c] + lnb1[c]);
                }
                *(bf16x8*)(out0 + (size_t)(m0 + row) * 256 + col) = o0;
                *(bf16x8*)(out1 + (size_t)(m0 + row) * 256 + col) = o1;
            } else {  // M_WPLN
                float s = lnb[row] + lnb[64 + row];
                float ss = lnb[32 + row] + lnb[96 + row];
                float mean = s * (1.0f / CH);
                float rstd = rsqrtf(ss * (1.0f / CH) - mean * mean + 1e-5f);
                bf16x8 o1;
#pragma unroll
                for (int e = 0; e < 8; ++e) {
                    int c = col + e;
                    o1[e] = (bf16)(((float)v[e] - mean) * rstd * lnw0[c] + lnb0[c]);
                }
                *(bf16x8*)(out0 + (size_t)(m0 + row) * 256 + col) = v;    // ATT raw
                *(bf16x8*)(out1 + (size_t)(m0 + row) * 256 + col) = o1;   // H
            }
        }
    }
}

// ---------------- wrapper kernels ----------------
#define SMEMSZ 34816

__global__ __launch_bounds__(256, 3) void conv_kernel(
    const bf16* padq, const bf16* padkv, const bf16* cw1, const bf16* cw2,
    const float* c1b, const float* c3b,
    bf16* qn, bf16* kvn, bf16* x3,
    const float* l1w, const float* l1b, const float* l10w, const float* l10b) {
    __shared__ __align__(16) char sm[SMEMSZ];
    if (blockIdx.y == 0)
        gemm_core<1, M_LN2, 576>(sm, padq, cw1, c1b, 1.0f, nullptr, qn, 256, kvn, nullptr,
                                 l1w, l1b, l10w, l10b);
    else
        gemm_core<1, M_DENSE, 576>(sm, padkv, cw2, c3b, 1.0f, nullptr, x3, 256, nullptr, nullptr,
                                   nullptr, nullptr, nullptr, nullptr);
}

__global__ __launch_bounds__(256, 3) void qkv_kernel(
    const bf16* qnp, const bf16* kvnp, const bf16* wqt, const bf16* wkvt,
    const float* bq, const float* bkv, bf16* q, bf16* kv) {
    __shared__ __align__(16) char sm[SMEMSZ];
    int by = blockIdx.y;
    const bf16* A = by ? kvnp : qnp;
    const bf16* B = by ? (wkvt + (size_t)(by - 1) * 65536) : wqt;
    const float* bias = by ? (bkv + (by - 1) * 256) : bq;
    float bsc = by ? 1.0f : SCQ;
    bf16* out = by ? (kv + (by - 1) * 256) : q;
    int ldo = by ? 512 : 256;
    gemm_core<0, M_DENSE, 256>(sm, A, B, bias, bsc, nullptr, out, ldo, nullptr, nullptr,
                               nullptr, nullptr, nullptr, nullptr);
}

__global__ __launch_bounds__(256, 3) void wp_kernel(
    const bf16* ao, const bf16* wpt, const float* bp, const bf16* x3,
    bf16* att, bf16* h, const float* l3w, const float* l3b) {
    __shared__ __align__(16) char sm[SMEMSZ];
    gemm_core<0, M_WPLN, 256>(sm, ao, wpt, bp, 1.0f, x3, att, 256, h, nullptr,
                              l3w, l3b, nullptr, nullptr);
}

__global__ __launch_bounds__(256, 3) void fc1_kernel(
    const bf16* h, const bf16* wf1, const float* f1b, bf16* m1) {
    __shared__ __align__(16) char sm[SMEMSZ];
    int by = blockIdx.y;
    gemm_core<0, M_GELU, 256>(sm, h, wf1 + (size_t)by * 65536, f1b + by * 256, 1.0f, nullptr,
                              m1 + by * 256, 512, nullptr, nullptr,
                              nullptr, nullptr, nullptr, nullptr);
}

__global__ __launch_bounds__(256, 3) void fc2_kernel(
    const bf16* m1, const bf16* wf2, const float* f2b, const bf16* att, float* out) {
    __shared__ __align__(16) char sm[SMEMSZ];
    gemm_core<0, M_NCHW, 512>(sm, m1, wf2, f2b, 1.0f, att, nullptr, 0, nullptr, out,
                              nullptr, nullptr, nullptr, nullptr);
}

// ---------------- neighborhood attention (3x3 window, 8 heads, hd=32) ----------------
__global__ __launch_bounds__(256) void attn_kernel(const bf16* __restrict__ q, const bf16* __restrict__ kv,
                                                   const float* __restrict__ rpb, bf16* __restrict__ out) {
    int idx = blockIdx.x * 256 + threadIdx.x;
    int h = idx & 7, p = idx >> 3;
    int b = p / IMG2;
    int rem = p - b * IMG2;
    int i = rem / IMG, j = rem - i * IMG;
    int si = i - 1; if (si < 0) si = 0; if (si > IMG - 3) si = IMG - 3;
    int sj = j - 1; if (sj < 0) sj = 0; if (sj > IMG - 3) sj = IMG - 3;
    int pi = i - si, pj = j - sj;

    float qv[32];
    {
        const bf16x8* qp = (const bf16x8*)(q + (size_t)p * CH + h * 32);
#pragma unroll
        for (int g = 0; g < 4; ++g) {
            bf16x8 t = qp[g];
#pragma unroll
            for (int e = 0; e < 8; ++e) qv[g * 8 + e] = (float)t[e];
        }
    }
    float logits[9];
#pragma unroll
    for (int a = 0; a < 3; ++a) {
#pragma unroll
        for (int bb = 0; bb < 3; ++bb) {
            int pn = (b * IMG + (si + a)) * IMG + (sj + bb);
            const bf16x8* kp = (const bf16x8*)(kv + (size_t)pn * 512 + h * 32);
            float s = 0.0f;
#pragma unroll
            for (int g = 0; g < 4; ++g) {
                bf16x8 t = kp[g];
#pragma unroll
                for (int e = 0; e < 8; ++e) s += qv[g * 8 + e] * (float)t[e];
            }
            logits[a * 3 + bb] = s + rpb[(h * 5 + (a - pi + 2)) * 5 + (bb - pj + 2)];
        }
    }
    float mx = logits[0];
#pragma unroll
    for (int n = 1; n < 9; ++n) mx = fmaxf(mx, logits[n]);
    float den = 0.0f;
#pragma unroll
    for (int n = 0; n < 9; ++n) { logits[n] = expf(logits[n] - mx); den += logits[n]; }
    float inv = 1.0f / den;
    float o[32] = {};
#pragma unroll
    for (int a = 0; a < 3; ++a) {
#pragma unroll
        for (int bb = 0; bb < 3; ++bb) {
            int pn = (b * IMG + (si + a)) * IMG + (sj + bb);
            float wgt = logits[a * 3 + bb] * inv;
            const bf16x8* vp = (const bf16x8*)(kv + (size_t)pn * 512 + 256 + h * 32);
#pragma unroll
            for (int g = 0; g < 4; ++g) {
                bf16x8 t = vp[g];
#pragma unroll
                for (int e = 0; e < 8; ++e) o[g * 8 + e] += wgt * (float)t[e];
            }
        }
    }
    bf16* op = out + (size_t)p * CH + h * 32;
#pragma unroll
    for (int g = 0; g < 4; ++g) {
        bf16x8 t;
#pragma unroll
        for (int e = 0; e < 8; ++e) t[e] = (bf16)o[g * 8 + e];
        *(bf16x8*)(op + g * 8) = t;
    }
}

extern "C" void kernel_launch(void* const* d_in, const int* in_sizes, int n_in,
                              void* d_out, int out_size, void* d_ws, size_t ws_size,
                              hipStream_t stream) {
    (void)in_sizes; (void)n_in; (void)out_size; (void)ws_size;
    const float* xq    = (const float*)d_in[0];
    const float* xkv   = (const float*)d_in[1];
    const float* c1w   = (const float*)d_in[2];
    const float* c1b   = (const float*)d_in[3];
    const float* c3w   = (const float*)d_in[4];
    const float* c3b   = (const float*)d_in[5];
    const float* ln1w  = (const float*)d_in[6];
    const float* ln1b  = (const float*)d_in[7];
    const float* ln10w = (const float*)d_in[8];
    const float* ln10b = (const float*)d_in[9];
    const float* ln3w  = (const float*)d_in[10];
    const float* ln3b  = (const float*)d_in[11];
    const float* wq    = (const float*)d_in[12];
    const float* bq    = (const float*)d_in[13];
    const float* wkv   = (const float*)d_in[14];
    const float* bkv   = (const float*)d_in[15];
    const float* rpb   = (const float*)d_in[16];
    const float* wp    = (const float*)d_in[17];
    const float* bp    = (const float*)d_in[18];
    const float* f1w   = (const float*)d_in[19];
    const float* f1b   = (const float*)d_in[20];
    const float* f2w   = (const float*)d_in[21];
    const float* f2b   = (const float*)d_in[22];
    float* out = (float*)d_out;

    char* ws = (char*)d_ws;
    bf16* PADQ  = (bf16*)(ws + 0);           // 3,326,976
    bf16* PADKV = (bf16*)(ws + 3326976);     // 3,326,976
    bf16* CW1   = (bf16*)(ws + 6653952);     //   294,912
    bf16* CW2   = (bf16*)(ws + 6948864);     //   294,912
    bf16* WQT   = (bf16*)(ws + 7243776);     //   131,072
    bf16* WKVT  = (bf16*)(ws + 7374848);     //   262,144
    bf16* WPT   = (bf16*)(ws + 7636992);     //   131,072
    bf16* WF1   = (bf16*)(ws + 7768064);     //   262,144
    bf16* WF2   = (bf16*)(ws + 8030208);     //   262,144
    bf16* QN    = (bf16*)(ws + 8292352);     // 12,845,056
    bf16* KVN   = (bf16*)(ws + 21137408);    // 12,845,056
    bf16* Q     = (bf16*)(ws + 33982464);    // 12,845,056
    bf16* KV    = (bf16*)(ws + 46827520);    // 25,690,112
    bf16* AO    = (bf16*)(ws + 72517632);    // 12,845,056
    bf16* X3    = (bf16*)(ws + 85362688);    // 12,845,056
    bf16* ATT   = (bf16*)(ws + 98207744);    // 12,845,056
    bf16* H     = (bf16*)(ws + 111052800);   // 12,845,056
    bf16* M1    = (bf16*)(ws + 123897856);   // 25,690,112 -> total 149,587,968

    prep_kernel<<<3072, 256, 0, stream>>>(xq, xkv, PADQ, PADKV, c1w, c3w, CW1, CW2,
                                          wq, WQT, wkv, WKVT, wp, WPT, f1w, WF1, f2w, WF2);
    conv_kernel<<<dim3(784, 2), 256, 0, stream>>>(PADQ, PADKV, CW1, CW2, c1b, c3b,
                                                  QN, KVN, X3, ln1w, ln1b, ln10w, ln10b);
    qkv_kernel<<<dim3(784, 3), 256, 0, stream>>>(QN, KVN, WQT, WKVT, bq, bkv, Q, KV);
    attn_kernel<<<784, 256, 0, stream>>>(Q, KV, rpb, AO);
    wp_kernel<<<784, 256, 0, stream>>>(AO, WPT, bp, X3, ATT, H, ln3w, ln3b);
    fc1_kernel<<<dim3(784, 2), 256, 0, stream>>>(H, WF1, f1b, M1);
    fc2_kernel<<<784, 256, 0, stream>>>(M1, WF2, f2b, ATT, out);
}